// Round 2
// baseline (6401.912 us; speedup 1.0000x reference)
//
#include <hip/hip_runtime.h>
#include <hip/hip_bf16.h>

#define N_NODES 100000
#define N_EDGES 1600000
#define IN_DIM 128
#define OUT_DIM 64
#define EDGE_DIM 32
#define NH 4
#define HD 16
#define NEG_SLOPE 0.2f

typedef __attribute__((ext_vector_type(8))) short short8;
typedef __attribute__((ext_vector_type(4))) float floatx4;

// Split an fp32 octet into bf16 hi/lo fragments: x = hi + lo + O(eps^2 * x).
// Using hi*hi + hi*lo + lo*hi MFMAs gives ~1e-5 relative dot-product error.
__device__ __forceinline__ void cvt_hilo(const float* __restrict__ p, short8& hi, short8& lo)
{
    float4 x0 = *(const float4*)p;
    float4 x1 = *(const float4*)(p + 4);
    float v[8] = {x0.x, x0.y, x0.z, x0.w, x1.x, x1.y, x1.z, x1.w};
#pragma unroll
    for (int j = 0; j < 8; ++j) {
        union { __hip_bfloat16 b; short s; } h, l;
        h.b = __float2bfloat16(v[j]);
        l.b = __float2bfloat16(v[j] - __bfloat162float(h.b));
        hi[j] = h.s;
        lo[j] = l.s;
    }
}

// ---------------------------------------------------------------------------
// Kernel A: feat_src = node_feat @ W_src^T, feat_dst = node_feat @ W_dst^T
// One wave per 16-node tile; 8 o-tiles (4 src + 4 dst); split-bf16 MFMA.
// A[m=lane&15][k=quad*8+j], B[n=lane&15][k=quad*8+j], C: col=lane&15, row=quad*4+r
// ---------------------------------------------------------------------------
__global__ __launch_bounds__(64) void node_proj_kernel(
    const float* __restrict__ node_feat,
    const float* __restrict__ W_src,
    const float* __restrict__ W_dst,
    float* __restrict__ feat_src,
    float* __restrict__ feat_dst)
{
    const int lane = threadIdx.x;
    const int col  = lane & 15;
    const int quad = lane >> 4;
    const int m0   = blockIdx.x * 16;

    floatx4 acc[8];
#pragma unroll
    for (int t = 0; t < 8; ++t) acc[t] = (floatx4){0.f, 0.f, 0.f, 0.f};

#pragma unroll
    for (int kc = 0; kc < 4; ++kc) {
        short8 ahi, alo;
        cvt_hilo(node_feat + (size_t)(m0 + col) * IN_DIM + kc * 32 + quad * 8, ahi, alo);
#pragma unroll
        for (int t = 0; t < 8; ++t) {
            const float* W = (t < 4) ? W_src : W_dst;
            int o = (t & 3) * 16 + col;
            short8 bhi, blo;
            cvt_hilo(W + (size_t)o * IN_DIM + kc * 32 + quad * 8, bhi, blo);
            acc[t] = __builtin_amdgcn_mfma_f32_16x16x32_bf16(ahi, bhi, acc[t], 0, 0, 0);
            acc[t] = __builtin_amdgcn_mfma_f32_16x16x32_bf16(ahi, blo, acc[t], 0, 0, 0);
            acc[t] = __builtin_amdgcn_mfma_f32_16x16x32_bf16(alo, bhi, acc[t], 0, 0, 0);
        }
    }

#pragma unroll
    for (int t = 0; t < 8; ++t) {
        float* out = (t < 4) ? feat_src : feat_dst;
        int ob = (t & 3) * 16;
#pragma unroll
        for (int r = 0; r < 4; ++r) {
            int node = m0 + quad * 4 + r;
            out[(size_t)node * OUT_DIM + ob + col] = acc[t][r];
        }
    }
}

// ---------------------------------------------------------------------------
// Kernel B: e_edge = edge_feat @ W_edge^T (split-bf16 MFMA, K=32);
// e = feat_src[src] + feat_dst[dst] + e_edge; leaky_relu; logits = sum(e*attn);
// ex = exp(logits) (no max-subtract: |logit| <~ 30, fp32-safe, alpha invariant);
// write ex into the alpha output slot (fp32); atomicAdd into seg_sum[dst].
// 4 waves/block, each wave handles 16 edges.
// ---------------------------------------------------------------------------
__global__ __launch_bounds__(256) void edge_logits_kernel(
    const float* __restrict__ edge_feat,
    const float* __restrict__ W_edge,
    const float* __restrict__ attn,
    const int* __restrict__ src,
    const int* __restrict__ dst,
    const float* __restrict__ feat_src,
    const float* __restrict__ feat_dst,
    float* __restrict__ ex_out,
    float* __restrict__ seg_sum)
{
    const int lane = threadIdx.x & 63;
    const int wave = threadIdx.x >> 6;
    const int col  = lane & 15;
    const int quad = lane >> 4;
    const size_t ebase = ((size_t)blockIdx.x * 4 + wave) * 16;

    short8 ahi, alo;
    cvt_hilo(edge_feat + (ebase + col) * EDGE_DIM + quad * 8, ahi, alo);

    floatx4 acc[4];
#pragma unroll
    for (int t = 0; t < 4; ++t) {
        short8 bhi, blo;
        cvt_hilo(W_edge + (size_t)(t * 16 + col) * EDGE_DIM + quad * 8, bhi, blo);
        floatx4 c = (floatx4){0.f, 0.f, 0.f, 0.f};
        c = __builtin_amdgcn_mfma_f32_16x16x32_bf16(ahi, bhi, c, 0, 0, 0);
        c = __builtin_amdgcn_mfma_f32_16x16x32_bf16(ahi, blo, c, 0, 0, 0);
        c = __builtin_amdgcn_mfma_f32_16x16x32_bf16(alo, bhi, c, 0, 0, 0);
        acc[t] = c;
    }

    // attn[h=t][hd=col]
    float att[4];
#pragma unroll
    for (int t = 0; t < 4; ++t) att[t] = attn[t * 16 + col];

    int s[4], d[4];
#pragma unroll
    for (int r = 0; r < 4; ++r) {
        s[r] = src[ebase + quad * 4 + r];
        d[r] = dst[ebase + quad * 4 + r];
    }

    // per (edge r, head t): leaky_relu then dot with attn across the 16 lanes
    float sums[16];
#pragma unroll
    for (int r = 0; r < 4; ++r) {
#pragma unroll
        for (int t = 0; t < 4; ++t) {
            float v = acc[t][r]
                    + feat_src[(size_t)s[r] * OUT_DIM + t * 16 + col]
                    + feat_dst[(size_t)d[r] * OUT_DIM + t * 16 + col];
            v = (v > 0.f) ? v : NEG_SLOPE * v;
            float p = v * att[t];
            p += __shfl_xor(p, 1);
            p += __shfl_xor(p, 2);
            p += __shfl_xor(p, 4);
            p += __shfl_xor(p, 8);
            sums[r * 4 + t] = p;   // identical across the 16 lanes of this quad
        }
    }

    // lane j in quad picks (r = j>>2, h = j&3); ex index collapses to ebase*4+lane
    const int j = col;
    const int rsel = j >> 2;
    float logit = sums[0];
#pragma unroll
    for (int i = 1; i < 16; ++i) logit = (j == i) ? sums[i] : logit;
    float ev = __expf(logit);
    ex_out[ebase * NH + lane] = ev;

    int dd = d[0];
#pragma unroll
    for (int r = 1; r < 4; ++r) dd = (rsel == r) ? d[r] : dd;
    atomicAdd(&seg_sum[(size_t)dd * NH + (j & 3)], ev);
}

// ---------------------------------------------------------------------------
// Kernel C: thread per (edge, head): alpha = ex / seg_sum[dst]; overwrite the
// alpha slot in-place (fp32); atomicAdd feat_src[src]*alpha into ft[dst].
// ---------------------------------------------------------------------------
__global__ __launch_bounds__(256) void scatter_kernel(
    const float* __restrict__ seg_sum,
    const float* __restrict__ feat_src,
    const int* __restrict__ src,
    const int* __restrict__ dst,
    float* __restrict__ ft,
    float* __restrict__ alpha_out)
{
    int g = blockIdx.x * 256 + threadIdx.x;   // g < E*NH = 6.4M
    int e = g >> 2;
    int h = g & 3;
    int s = src[e];
    int d = dst[e];
    float aval = alpha_out[g] / seg_sum[(size_t)d * NH + h];
    alpha_out[g] = aval;

    const float* fs = feat_src + (size_t)s * OUT_DIM + h * HD;
    float* fo = ft + (size_t)d * OUT_DIM + h * HD;
#pragma unroll
    for (int i = 0; i < HD; ++i) {
        atomicAdd(fo + i, fs[i] * aval);
    }
}

// ---------------------------------------------------------------------------
// Kernel D: rst = ft + bias (fp32 out)
// ---------------------------------------------------------------------------
__global__ __launch_bounds__(256) void finalize_kernel(
    const float* __restrict__ ft,
    const float* __restrict__ bias,
    float* __restrict__ out)
{
    int g = blockIdx.x * 256 + threadIdx.x;   // g < N*OUT_DIM = 6.4M
    out[g] = ft[g] + bias[g & (OUT_DIM - 1)];
}

// ---------------------------------------------------------------------------
extern "C" void kernel_launch(void* const* d_in, const int* in_sizes, int n_in,
                              void* d_out, int out_size, void* d_ws, size_t ws_size,
                              hipStream_t stream)
{
    const float* node_feat = (const float*)d_in[0];
    const float* edge_feat = (const float*)d_in[1];
    const float* W_src     = (const float*)d_in[2];
    const float* W_dst     = (const float*)d_in[3];
    const float* W_edge    = (const float*)d_in[4];
    const float* attn      = (const float*)d_in[5];
    const float* bias      = (const float*)d_in[6];
    const int* src = (const int*)d_in[7];
    const int* dst = (const int*)d_in[8];

    // workspace (fp32): feat_src | feat_dst | seg_sum | ft   (~78.4 MB)
    float* ws       = (float*)d_ws;
    float* feat_src = ws;
    float* feat_dst = feat_src + (size_t)N_NODES * OUT_DIM;
    float* seg_sum  = feat_dst + (size_t)N_NODES * OUT_DIM;
    float* ft       = seg_sum  + (size_t)N_NODES * NH;

    float* rst_out   = (float*)d_out;
    float* alpha_out = rst_out + (size_t)N_NODES * OUT_DIM;   // also holds ex pre-normalize

    hipMemsetAsync(seg_sum, 0, (size_t)N_NODES * NH * sizeof(float), stream);
    hipMemsetAsync(ft, 0, (size_t)N_NODES * OUT_DIM * sizeof(float), stream);

    node_proj_kernel<<<N_NODES / 16, 64, 0, stream>>>(node_feat, W_src, W_dst, feat_src, feat_dst);
    edge_logits_kernel<<<N_EDGES / 64, 256, 0, stream>>>(edge_feat, W_edge, attn, src, dst,
                                                         feat_src, feat_dst, alpha_out, seg_sum);
    scatter_kernel<<<(N_EDGES * NH) / 256, 256, 0, stream>>>(seg_sum, feat_src, src, dst,
                                                             ft, alpha_out);
    finalize_kernel<<<((size_t)N_NODES * OUT_DIM) / 256, 256, 0, stream>>>(ft, bias, rst_out);
}

// Round 3
// 1153.599 us; speedup vs baseline: 5.5495x; 5.5495x over previous
//
#include <hip/hip_runtime.h>
#include <hip/hip_bf16.h>

#define N_NODES 100000
#define N_EDGES 1600000
#define IN_DIM 128
#define OUT_DIM 64
#define EDGE_DIM 32
#define NH 4
#define HD 16
#define NEG_SLOPE 0.2f

typedef __attribute__((ext_vector_type(8))) short short8;
typedef __attribute__((ext_vector_type(4))) float floatx4;

// Split an fp32 octet into bf16 hi/lo fragments: x = hi + lo + O(eps^2 * x).
// hi*hi + hi*lo + lo*hi MFMAs give ~1e-5 relative dot-product error.
__device__ __forceinline__ void cvt_hilo(const float* __restrict__ p, short8& hi, short8& lo)
{
    float4 x0 = *(const float4*)p;
    float4 x1 = *(const float4*)(p + 4);
    float v[8] = {x0.x, x0.y, x0.z, x0.w, x1.x, x1.y, x1.z, x1.w};
#pragma unroll
    for (int j = 0; j < 8; ++j) {
        union { __hip_bfloat16 b; short s; } h, l;
        h.b = __float2bfloat16(v[j]);
        l.b = __float2bfloat16(v[j] - __bfloat162float(h.b));
        hi[j] = h.s;
        lo[j] = l.s;
    }
}

// ---------------------------------------------------------------------------
// Kernel A: feat_src = node_feat @ W_src^T, feat_dst = node_feat @ W_dst^T
// One wave per 16-node tile; 8 o-tiles (4 src + 4 dst); split-bf16 MFMA.
// ---------------------------------------------------------------------------
__global__ __launch_bounds__(64) void node_proj_kernel(
    const float* __restrict__ node_feat,
    const float* __restrict__ W_src,
    const float* __restrict__ W_dst,
    float* __restrict__ feat_src,
    float* __restrict__ feat_dst)
{
    const int lane = threadIdx.x;
    const int col  = lane & 15;
    const int quad = lane >> 4;
    const int m0   = blockIdx.x * 16;

    floatx4 acc[8];
#pragma unroll
    for (int t = 0; t < 8; ++t) acc[t] = (floatx4){0.f, 0.f, 0.f, 0.f};

#pragma unroll
    for (int kc = 0; kc < 4; ++kc) {
        short8 ahi, alo;
        cvt_hilo(node_feat + (size_t)(m0 + col) * IN_DIM + kc * 32 + quad * 8, ahi, alo);
#pragma unroll
        for (int t = 0; t < 8; ++t) {
            const float* W = (t < 4) ? W_src : W_dst;
            int o = (t & 3) * 16 + col;
            short8 bhi, blo;
            cvt_hilo(W + (size_t)o * IN_DIM + kc * 32 + quad * 8, bhi, blo);
            acc[t] = __builtin_amdgcn_mfma_f32_16x16x32_bf16(ahi, bhi, acc[t], 0, 0, 0);
            acc[t] = __builtin_amdgcn_mfma_f32_16x16x32_bf16(ahi, blo, acc[t], 0, 0, 0);
            acc[t] = __builtin_amdgcn_mfma_f32_16x16x32_bf16(alo, bhi, acc[t], 0, 0, 0);
        }
    }

#pragma unroll
    for (int t = 0; t < 8; ++t) {
        float* out = (t < 4) ? feat_src : feat_dst;
        int ob = (t & 3) * 16;
#pragma unroll
        for (int r = 0; r < 4; ++r) {
            int node = m0 + quad * 4 + r;
            out[(size_t)node * OUT_DIM + ob + col] = acc[t][r];
        }
    }
}

// ---------------------------------------------------------------------------
// Kernel B: edge logits + exp; atomicAdd seg_sum[dst]; degree histogram folded
// in (one lane per edge). ex written to the alpha output slot.
// ---------------------------------------------------------------------------
__global__ __launch_bounds__(256) void edge_logits_kernel(
    const float* __restrict__ edge_feat,
    const float* __restrict__ W_edge,
    const float* __restrict__ attn,
    const int* __restrict__ src,
    const int* __restrict__ dst,
    const float* __restrict__ feat_src,
    const float* __restrict__ feat_dst,
    float* __restrict__ ex_out,
    float* __restrict__ seg_sum,
    int* __restrict__ deg)
{
    const int lane = threadIdx.x & 63;
    const int wave = threadIdx.x >> 6;
    const int col  = lane & 15;
    const int quad = lane >> 4;
    const size_t ebase = ((size_t)blockIdx.x * 4 + wave) * 16;

    short8 ahi, alo;
    cvt_hilo(edge_feat + (ebase + col) * EDGE_DIM + quad * 8, ahi, alo);

    floatx4 acc[4];
#pragma unroll
    for (int t = 0; t < 4; ++t) {
        short8 bhi, blo;
        cvt_hilo(W_edge + (size_t)(t * 16 + col) * EDGE_DIM + quad * 8, bhi, blo);
        floatx4 c = (floatx4){0.f, 0.f, 0.f, 0.f};
        c = __builtin_amdgcn_mfma_f32_16x16x32_bf16(ahi, bhi, c, 0, 0, 0);
        c = __builtin_amdgcn_mfma_f32_16x16x32_bf16(ahi, blo, c, 0, 0, 0);
        c = __builtin_amdgcn_mfma_f32_16x16x32_bf16(alo, bhi, c, 0, 0, 0);
        acc[t] = c;
    }

    float att[4];
#pragma unroll
    for (int t = 0; t < 4; ++t) att[t] = attn[t * 16 + col];

    int s[4], d[4];
#pragma unroll
    for (int r = 0; r < 4; ++r) {
        s[r] = src[ebase + quad * 4 + r];
        d[r] = dst[ebase + quad * 4 + r];
    }

    float sums[16];
#pragma unroll
    for (int r = 0; r < 4; ++r) {
#pragma unroll
        for (int t = 0; t < 4; ++t) {
            float v = acc[t][r]
                    + feat_src[(size_t)s[r] * OUT_DIM + t * 16 + col]
                    + feat_dst[(size_t)d[r] * OUT_DIM + t * 16 + col];
            v = (v > 0.f) ? v : NEG_SLOPE * v;
            float p = v * att[t];
            p += __shfl_xor(p, 1);
            p += __shfl_xor(p, 2);
            p += __shfl_xor(p, 4);
            p += __shfl_xor(p, 8);
            sums[r * 4 + t] = p;
        }
    }

    // lane j in quad picks (r = j>>2, h = j&3); ex index collapses to ebase*4+lane
    const int j = col;
    const int rsel = j >> 2;
    float logit = sums[0];
#pragma unroll
    for (int i = 1; i < 16; ++i) logit = (j == i) ? sums[i] : logit;
    float ev = __expf(logit);
    ex_out[ebase * NH + lane] = ev;

    int dd = d[0];
#pragma unroll
    for (int r = 1; r < 4; ++r) dd = (rsel == r) ? d[r] : dd;
    atomicAdd(&seg_sum[(size_t)dd * NH + (j & 3)], ev);
    if ((j & 3) == 0) atomicAdd(&deg[dd], 1);   // one lane per edge
}

// ---------------------------------------------------------------------------
// Kernel S: single-block exclusive scan of deg[N] -> row_ptr[N+1], cursor[N].
// ---------------------------------------------------------------------------
__global__ __launch_bounds__(1024) void scan_kernel(
    const int* __restrict__ deg,
    int* __restrict__ row_ptr,
    int* __restrict__ cursor)
{
    __shared__ int partials[1024];
    const int tid = threadIdx.x;
    const int per = (N_NODES + 1023) / 1024;   // 98
    const int base = tid * per;

    int sum = 0;
    for (int i = 0; i < per; ++i) {
        int idx = base + i;
        if (idx < N_NODES) sum += deg[idx];
    }
    partials[tid] = sum;
    __syncthreads();

    for (int off = 1; off < 1024; off <<= 1) {
        int v = partials[tid];
        int add = (tid >= off) ? partials[tid - off] : 0;
        __syncthreads();
        partials[tid] = v + add;
        __syncthreads();
    }

    int prefix = (tid > 0) ? partials[tid - 1] : 0;
    for (int i = 0; i < per; ++i) {
        int idx = base + i;
        if (idx < N_NODES) {
            row_ptr[idx] = prefix;
            cursor[idx]  = prefix;
            prefix += deg[idx];
        }
    }
    if (tid == 1023) row_ptr[N_NODES] = partials[1023];
}

// ---------------------------------------------------------------------------
// Kernel F: bucket-fill — eidx[cursor[dst[e]]++] = e
// ---------------------------------------------------------------------------
__global__ __launch_bounds__(256) void bucket_fill_kernel(
    const int* __restrict__ dst,
    int* __restrict__ cursor,
    int* __restrict__ eidx)
{
    int e = blockIdx.x * 256 + threadIdx.x;
    int pos = atomicAdd(&cursor[dst[e]], 1);
    eidx[pos] = e;
}

// ---------------------------------------------------------------------------
// Kernel C: alpha = ex / seg_sum[dst] (in place in the alpha output slot)
// ---------------------------------------------------------------------------
__global__ __launch_bounds__(256) void normalize_kernel(
    const float* __restrict__ seg_sum,
    const int* __restrict__ dst,
    float* __restrict__ alpha)
{
    int g = blockIdx.x * 256 + threadIdx.x;   // g < E*NH
    int e = g >> 2;
    int h = g & 3;
    alpha[g] = alpha[g] / seg_sum[(size_t)dst[e] * NH + h];
}

// ---------------------------------------------------------------------------
// Kernel G: gather-side aggregation. One wave per node; lane = h*16+hd.
// out[n] = sum_{e in bucket(n)} feat_src[src[e]] * alpha[e,h]  + bias
// ---------------------------------------------------------------------------
__global__ __launch_bounds__(256) void aggregate_kernel(
    const int* __restrict__ row_ptr,
    const int* __restrict__ eidx,
    const int* __restrict__ src,
    const float* __restrict__ alpha,
    const float* __restrict__ feat_src,
    const float* __restrict__ bias,
    float* __restrict__ out)
{
    const int node = blockIdx.x * 4 + (threadIdx.x >> 6);
    if (node >= N_NODES) return;
    const int lane = threadIdx.x & 63;
    const int h = lane >> 4;

    const int start = row_ptr[node];
    const int end   = row_ptr[node + 1];

    float acc = 0.f;
    int j = start;
    // software pipeline: prefetch edge id + src node one iteration ahead
    int e_cur = 0, s_cur = 0;
    if (j < end) { e_cur = eidx[j]; s_cur = src[e_cur]; }
    for (; j < end; ++j) {
        int e = e_cur, s = s_cur;
        if (j + 1 < end) { e_cur = eidx[j + 1]; s_cur = src[e_cur]; }
        float aval = alpha[(size_t)e * NH + h];
        acc += feat_src[(size_t)s * OUT_DIM + lane] * aval;
    }
    out[(size_t)node * OUT_DIM + lane] = acc + bias[lane];
}

// ---------------------------------------------------------------------------
extern "C" void kernel_launch(void* const* d_in, const int* in_sizes, int n_in,
                              void* d_out, int out_size, void* d_ws, size_t ws_size,
                              hipStream_t stream)
{
    const float* node_feat = (const float*)d_in[0];
    const float* edge_feat = (const float*)d_in[1];
    const float* W_src     = (const float*)d_in[2];
    const float* W_dst     = (const float*)d_in[3];
    const float* W_edge    = (const float*)d_in[4];
    const float* attn      = (const float*)d_in[5];
    const float* bias      = (const float*)d_in[6];
    const int* src = (const int*)d_in[7];
    const int* dst = (const int*)d_in[8];

    // workspace: feat_src | feat_dst | seg_sum | deg | row_ptr | cursor | eidx  (~60 MB)
    float* ws       = (float*)d_ws;
    float* feat_src = ws;
    float* feat_dst = feat_src + (size_t)N_NODES * OUT_DIM;
    float* seg_sum  = feat_dst + (size_t)N_NODES * OUT_DIM;
    int*   deg      = (int*)(seg_sum + (size_t)N_NODES * NH);
    int*   row_ptr  = deg + N_NODES;
    int*   cursor   = row_ptr + N_NODES + 1;
    int*   eidx     = cursor + N_NODES;

    float* rst_out   = (float*)d_out;
    float* alpha_out = rst_out + (size_t)N_NODES * OUT_DIM;   // holds ex, then alpha

    hipMemsetAsync(seg_sum, 0, (size_t)N_NODES * NH * sizeof(float), stream);
    hipMemsetAsync(deg, 0, (size_t)N_NODES * sizeof(int), stream);

    node_proj_kernel<<<N_NODES / 16, 64, 0, stream>>>(node_feat, W_src, W_dst, feat_src, feat_dst);
    edge_logits_kernel<<<N_EDGES / 64, 256, 0, stream>>>(edge_feat, W_edge, attn, src, dst,
                                                         feat_src, feat_dst, alpha_out, seg_sum, deg);
    scan_kernel<<<1, 1024, 0, stream>>>(deg, row_ptr, cursor);
    bucket_fill_kernel<<<N_EDGES / 256, 256, 0, stream>>>(dst, cursor, eidx);
    normalize_kernel<<<(N_EDGES * NH) / 256, 256, 0, stream>>>(seg_sum, dst, alpha_out);
    aggregate_kernel<<<(N_NODES + 3) / 4, 256, 0, stream>>>(row_ptr, eidx, src, alpha_out,
                                                            feat_src, bias, rst_out);
}

// Round 4
// 879.061 us; speedup vs baseline: 7.2827x; 1.3123x over previous
//
#include <hip/hip_runtime.h>
#include <hip/hip_bf16.h>

#define N_NODES 100000
#define N_EDGES 1600000
#define IN_DIM 128
#define OUT_DIM 64
#define EDGE_DIM 32
#define NH 4
#define HD 16
#define NEG_SLOPE 0.2f

#define W_SRC_ELEMS (OUT_DIM * IN_DIM)   // 8192
#define W_EDGE_ELEMS (OUT_DIM * EDGE_DIM) // 2048
#define W_TOTAL (2 * W_SRC_ELEMS + W_EDGE_ELEMS) // 18432

typedef __attribute__((ext_vector_type(8))) short short8;
typedef __attribute__((ext_vector_type(4))) float floatx4;

// Split an fp32 octet into bf16 hi/lo fragments: x = hi + lo + O(eps^2 * x).
// hi*hi + hi*lo + lo*hi MFMAs give ~1e-5 relative dot-product error.
__device__ __forceinline__ void cvt_hilo(const float* __restrict__ p, short8& hi, short8& lo)
{
    float4 x0 = *(const float4*)p;
    float4 x1 = *(const float4*)(p + 4);
    float v[8] = {x0.x, x0.y, x0.z, x0.w, x1.x, x1.y, x1.z, x1.w};
#pragma unroll
    for (int j = 0; j < 8; ++j) {
        union { __hip_bfloat16 b; short s; } h, l;
        h.b = __float2bfloat16(v[j]);
        l.b = __float2bfloat16(v[j] - __bfloat162float(h.b));
        hi[j] = h.s;
        lo[j] = l.s;
    }
}

// ---------------------------------------------------------------------------
// Kernel W: precompute hi/lo bf16 split of W_src|W_dst|W_edge (one pass).
// ---------------------------------------------------------------------------
__global__ __launch_bounds__(256) void wsplit_kernel(
    const float* __restrict__ W_src,
    const float* __restrict__ W_dst,
    const float* __restrict__ W_edge,
    short* __restrict__ w_hi,
    short* __restrict__ w_lo)
{
    int g = blockIdx.x * 256 + threadIdx.x;
    if (g >= W_TOTAL) return;
    float v;
    if (g < W_SRC_ELEMS)            v = W_src[g];
    else if (g < 2 * W_SRC_ELEMS)   v = W_dst[g - W_SRC_ELEMS];
    else                            v = W_edge[g - 2 * W_SRC_ELEMS];
    union { __hip_bfloat16 b; short s; } h, l;
    h.b = __float2bfloat16(v);
    l.b = __float2bfloat16(v - __bfloat162float(h.b));
    w_hi[g] = h.s;
    w_lo[g] = l.s;
}

// ---------------------------------------------------------------------------
// Kernel A: feat_src = node_feat @ W_src^T, feat_dst = node_feat @ W_dst^T
// One wave per 16-node tile; 8 o-tiles (4 src + 4 dst); split-bf16 MFMA.
// W frags come precomputed from w_hi/w_lo.
// ---------------------------------------------------------------------------
__global__ __launch_bounds__(64) void node_proj_kernel(
    const float* __restrict__ node_feat,
    const short* __restrict__ w_hi,
    const short* __restrict__ w_lo,
    float* __restrict__ feat_src,
    float* __restrict__ feat_dst)
{
    const int lane = threadIdx.x;
    const int col  = lane & 15;
    const int quad = lane >> 4;
    const int m0   = blockIdx.x * 16;

    floatx4 acc[8];
#pragma unroll
    for (int t = 0; t < 8; ++t) acc[t] = (floatx4){0.f, 0.f, 0.f, 0.f};

#pragma unroll
    for (int kc = 0; kc < 4; ++kc) {
        short8 ahi, alo;
        cvt_hilo(node_feat + (size_t)(m0 + col) * IN_DIM + kc * 32 + quad * 8, ahi, alo);
#pragma unroll
        for (int t = 0; t < 8; ++t) {
            // W_src rows 0..63 then W_dst rows 0..63 (contiguous in w_hi/w_lo)
            int o = (t < 4 ? 0 : OUT_DIM) + (t & 3) * 16 + col;
            size_t off = (size_t)o * IN_DIM + kc * 32 + quad * 8;
            short8 bhi = *(const short8*)(w_hi + off);
            short8 blo = *(const short8*)(w_lo + off);
            acc[t] = __builtin_amdgcn_mfma_f32_16x16x32_bf16(ahi, bhi, acc[t], 0, 0, 0);
            acc[t] = __builtin_amdgcn_mfma_f32_16x16x32_bf16(ahi, blo, acc[t], 0, 0, 0);
            acc[t] = __builtin_amdgcn_mfma_f32_16x16x32_bf16(alo, bhi, acc[t], 0, 0, 0);
        }
    }

#pragma unroll
    for (int t = 0; t < 8; ++t) {
        float* out = (t < 4) ? feat_src : feat_dst;
        int ob = (t & 3) * 16;
#pragma unroll
        for (int r = 0; r < 4; ++r) {
            int node = m0 + quad * 4 + r;
            out[(size_t)node * OUT_DIM + ob + col] = acc[t][r];
        }
    }
}

// ---------------------------------------------------------------------------
// Kernel B: edge logits + exp; atomicAdd seg_sum[dst]; degree histogram folded
// in (one lane per edge). ex written to the alpha output slot.
// ---------------------------------------------------------------------------
__global__ __launch_bounds__(256) void edge_logits_kernel(
    const float* __restrict__ edge_feat,
    const short* __restrict__ we_hi,   // W_edge hi, [64][32]
    const short* __restrict__ we_lo,
    const float* __restrict__ attn,
    const int* __restrict__ src,
    const int* __restrict__ dst,
    const float* __restrict__ feat_src,
    const float* __restrict__ feat_dst,
    float* __restrict__ ex_out,
    float* __restrict__ seg_sum,
    int* __restrict__ deg)
{
    const int lane = threadIdx.x & 63;
    const int wave = threadIdx.x >> 6;
    const int col  = lane & 15;
    const int quad = lane >> 4;
    const size_t ebase = ((size_t)blockIdx.x * 4 + wave) * 16;

    short8 ahi, alo;
    cvt_hilo(edge_feat + (ebase + col) * EDGE_DIM + quad * 8, ahi, alo);

    floatx4 acc[4];
#pragma unroll
    for (int t = 0; t < 4; ++t) {
        size_t off = (size_t)(t * 16 + col) * EDGE_DIM + quad * 8;
        short8 bhi = *(const short8*)(we_hi + off);
        short8 blo = *(const short8*)(we_lo + off);
        floatx4 c = (floatx4){0.f, 0.f, 0.f, 0.f};
        c = __builtin_amdgcn_mfma_f32_16x16x32_bf16(ahi, bhi, c, 0, 0, 0);
        c = __builtin_amdgcn_mfma_f32_16x16x32_bf16(ahi, blo, c, 0, 0, 0);
        c = __builtin_amdgcn_mfma_f32_16x16x32_bf16(alo, bhi, c, 0, 0, 0);
        acc[t] = c;
    }

    float att[4];
#pragma unroll
    for (int t = 0; t < 4; ++t) att[t] = attn[t * 16 + col];

    int s[4], d[4];
#pragma unroll
    for (int r = 0; r < 4; ++r) {
        s[r] = src[ebase + quad * 4 + r];
        d[r] = dst[ebase + quad * 4 + r];
    }

    float sums[16];
#pragma unroll
    for (int r = 0; r < 4; ++r) {
#pragma unroll
        for (int t = 0; t < 4; ++t) {
            float v = acc[t][r]
                    + feat_src[(size_t)s[r] * OUT_DIM + t * 16 + col]
                    + feat_dst[(size_t)d[r] * OUT_DIM + t * 16 + col];
            v = (v > 0.f) ? v : NEG_SLOPE * v;
            float p = v * att[t];
            p += __shfl_xor(p, 1);
            p += __shfl_xor(p, 2);
            p += __shfl_xor(p, 4);
            p += __shfl_xor(p, 8);
            sums[r * 4 + t] = p;
        }
    }

    // lane j in quad picks (r = j>>2, h = j&3); ex index collapses to ebase*4+lane
    const int j = col;
    const int rsel = j >> 2;
    float logit = sums[0];
#pragma unroll
    for (int i = 1; i < 16; ++i) logit = (j == i) ? sums[i] : logit;
    float ev = __expf(logit);
    ex_out[ebase * NH + lane] = ev;

    int dd = d[0];
#pragma unroll
    for (int r = 1; r < 4; ++r) dd = (rsel == r) ? d[r] : dd;
    atomicAdd(&seg_sum[(size_t)dd * NH + (j & 3)], ev);
    if ((j & 3) == 0) atomicAdd(&deg[dd], 1);   // one lane per edge
}

// ---------------------------------------------------------------------------
// Hierarchical scan of deg[N] -> row_ptr[N+1] (exclusive), cursor[N].
// Phase 1: 98 blocks x 256 thr, 4 elems/thr -> partial[98]
// Phase 2: 1 block scans partial[98] -> block_off[98]; row_ptr[N]=E
// Phase 3: 98 blocks: in-block scan + block_off -> row_ptr/cursor
// ---------------------------------------------------------------------------
#define SCAN_BLOCKS 98

__global__ __launch_bounds__(256) void scan_phase1(
    const int* __restrict__ deg, int* __restrict__ partial)
{
    __shared__ int red[256];
    const int tid = threadIdx.x;
    const int base = blockIdx.x * 1024 + tid * 4;
    int s = 0;
#pragma unroll
    for (int i = 0; i < 4; ++i) {
        int idx = base + i;
        if (idx < N_NODES) s += deg[idx];
    }
    red[tid] = s;
    __syncthreads();
    for (int off = 128; off > 0; off >>= 1) {
        if (tid < off) red[tid] += red[tid + off];
        __syncthreads();
    }
    if (tid == 0) partial[blockIdx.x] = red[0];
}

__global__ __launch_bounds__(128) void scan_phase2(
    const int* __restrict__ partial, int* __restrict__ block_off, int* __restrict__ row_ptr)
{
    __shared__ int buf[128];
    const int tid = threadIdx.x;
    buf[tid] = (tid < SCAN_BLOCKS) ? partial[tid] : 0;
    __syncthreads();
    for (int off = 1; off < 128; off <<= 1) {
        int v = buf[tid];
        int add = (tid >= off) ? buf[tid - off] : 0;
        __syncthreads();
        buf[tid] = v + add;
        __syncthreads();
    }
    if (tid < SCAN_BLOCKS) block_off[tid] = (tid > 0) ? buf[tid - 1] : 0;
    if (tid == 0) row_ptr[N_NODES] = N_EDGES;
}

__global__ __launch_bounds__(256) void scan_phase3(
    const int* __restrict__ deg, const int* __restrict__ block_off,
    int* __restrict__ row_ptr, int* __restrict__ cursor)
{
    __shared__ int tsum[256];
    const int tid = threadIdx.x;
    const int base = blockIdx.x * 1024 + tid * 4;
    int d[4];
    int s = 0;
#pragma unroll
    for (int i = 0; i < 4; ++i) {
        int idx = base + i;
        d[i] = (idx < N_NODES) ? deg[idx] : 0;
        s += d[i];
    }
    tsum[tid] = s;
    __syncthreads();
    for (int off = 1; off < 256; off <<= 1) {
        int v = tsum[tid];
        int add = (tid >= off) ? tsum[tid - off] : 0;
        __syncthreads();
        tsum[tid] = v + add;
        __syncthreads();
    }
    int prefix = block_off[blockIdx.x] + ((tid > 0) ? tsum[tid - 1] : 0);
#pragma unroll
    for (int i = 0; i < 4; ++i) {
        int idx = base + i;
        if (idx < N_NODES) {
            row_ptr[idx] = prefix;
            cursor[idx]  = prefix;
            prefix += d[i];
        }
    }
}

// ---------------------------------------------------------------------------
// Kernel F: bucket-fill — eidx[cursor[dst[e]]++] = e
// ---------------------------------------------------------------------------
__global__ __launch_bounds__(256) void bucket_fill_kernel(
    const int* __restrict__ dst,
    int* __restrict__ cursor,
    int* __restrict__ eidx)
{
    int e = blockIdx.x * 256 + threadIdx.x;
    int pos = atomicAdd(&cursor[dst[e]], 1);
    eidx[pos] = e;
}

// ---------------------------------------------------------------------------
// Kernel C: alpha = ex / seg_sum[dst] (in place in the alpha output slot)
// ---------------------------------------------------------------------------
__global__ __launch_bounds__(256) void normalize_kernel(
    const float* __restrict__ seg_sum,
    const int* __restrict__ dst,
    float* __restrict__ alpha)
{
    int g = blockIdx.x * 256 + threadIdx.x;   // g < E*NH
    int e = g >> 2;
    int h = g & 3;
    alpha[g] = alpha[g] / seg_sum[(size_t)dst[e] * NH + h];
}

// ---------------------------------------------------------------------------
// Kernel G: gather-side aggregation. One wave per node; lane = h*16+hd.
// out[n] = sum_{e in bucket(n)} feat_src[src[e]] * alpha[e,h]  + bias
// ---------------------------------------------------------------------------
__global__ __launch_bounds__(256) void aggregate_kernel(
    const int* __restrict__ row_ptr,
    const int* __restrict__ eidx,
    const int* __restrict__ src,
    const float* __restrict__ alpha,
    const float* __restrict__ feat_src,
    const float* __restrict__ bias,
    float* __restrict__ out)
{
    const int node = blockIdx.x * 4 + (threadIdx.x >> 6);
    if (node >= N_NODES) return;
    const int lane = threadIdx.x & 63;
    const int h = lane >> 4;

    const int start = row_ptr[node];
    const int end   = row_ptr[node + 1];

    float acc = 0.f;
    int j = start;
    int e_cur = 0, s_cur = 0;
    if (j < end) { e_cur = eidx[j]; s_cur = src[e_cur]; }
    for (; j < end; ++j) {
        int e = e_cur, s = s_cur;
        if (j + 1 < end) { e_cur = eidx[j + 1]; s_cur = src[e_cur]; }
        float aval = alpha[(size_t)e * NH + h];
        acc += feat_src[(size_t)s * OUT_DIM + lane] * aval;
    }
    out[(size_t)node * OUT_DIM + lane] = acc + bias[lane];
}

// ---------------------------------------------------------------------------
extern "C" void kernel_launch(void* const* d_in, const int* in_sizes, int n_in,
                              void* d_out, int out_size, void* d_ws, size_t ws_size,
                              hipStream_t stream)
{
    const float* node_feat = (const float*)d_in[0];
    const float* edge_feat = (const float*)d_in[1];
    const float* W_src     = (const float*)d_in[2];
    const float* W_dst     = (const float*)d_in[3];
    const float* W_edge    = (const float*)d_in[4];
    const float* attn      = (const float*)d_in[5];
    const float* bias      = (const float*)d_in[6];
    const int* src = (const int*)d_in[7];
    const int* dst = (const int*)d_in[8];

    // workspace layout
    float* ws       = (float*)d_ws;
    float* feat_src = ws;                                        // 6.4M floats
    float* feat_dst = feat_src + (size_t)N_NODES * OUT_DIM;      // 6.4M floats
    float* seg_sum  = feat_dst + (size_t)N_NODES * OUT_DIM;      // 400K floats
    int*   deg      = (int*)(seg_sum + (size_t)N_NODES * NH);    // 100K ints
    int*   row_ptr  = deg + N_NODES;                             // 100K+1
    int*   cursor   = row_ptr + N_NODES + 1;                     // 100K
    int*   eidx     = cursor + N_NODES;                          // 1.6M
    int*   partial  = eidx + N_EDGES;                            // 98
    int*   boff     = partial + 128;                             // 98
    short* w_hi     = (short*)(boff + 128);                      // 18432 shorts
    short* w_lo     = w_hi + W_TOTAL;

    float* rst_out   = (float*)d_out;
    float* alpha_out = rst_out + (size_t)N_NODES * OUT_DIM;   // holds ex, then alpha

    hipMemsetAsync(seg_sum, 0, (size_t)N_NODES * NH * sizeof(float), stream);
    hipMemsetAsync(deg, 0, (size_t)N_NODES * sizeof(int), stream);

    wsplit_kernel<<<(W_TOTAL + 255) / 256, 256, 0, stream>>>(W_src, W_dst, W_edge, w_hi, w_lo);
    node_proj_kernel<<<N_NODES / 16, 64, 0, stream>>>(node_feat, w_hi, w_lo, feat_src, feat_dst);
    edge_logits_kernel<<<N_EDGES / 64, 256, 0, stream>>>(edge_feat,
                                                         w_hi + 2 * W_SRC_ELEMS, w_lo + 2 * W_SRC_ELEMS,
                                                         attn, src, dst,
                                                         feat_src, feat_dst, alpha_out, seg_sum, deg);
    scan_phase1<<<SCAN_BLOCKS, 256, 0, stream>>>(deg, partial);
    scan_phase2<<<1, 128, 0, stream>>>(partial, boff, row_ptr);
    scan_phase3<<<SCAN_BLOCKS, 256, 0, stream>>>(deg, boff, row_ptr, cursor);
    bucket_fill_kernel<<<N_EDGES / 256, 256, 0, stream>>>(dst, cursor, eidx);
    normalize_kernel<<<(N_EDGES * NH) / 256, 256, 0, stream>>>(seg_sum, dst, alpha_out);
    aggregate_kernel<<<(N_NODES + 3) / 4, 256, 0, stream>>>(row_ptr, eidx, src, alpha_out,
                                                            feat_src, bias, rst_out);
}